// Round 1
// baseline (293.852 us; speedup 1.0000x reference)
//
#include <hip/hip_runtime.h>
#include <hip/hip_bf16.h>

// Fused MHA, B=8, S=1024, H=8, DK=128, D=1024, fp32 in/out, bf16 MFMA compute.
// Pipeline: convert -> Qproj -> Kproj -> Vproj(transposed out) -> flash attn
// (fused attn_arrange pack into ret) -> out proj (fp32 to d_out).

typedef __attribute__((ext_vector_type(8))) __bf16 bf16x8;
typedef __attribute__((ext_vector_type(4))) float f32x4;

#define DEV static __device__ __forceinline__

DEV unsigned short f2bf(float f) {
  union { float f; unsigned int u; } c; c.f = f;
  unsigned int u = c.u + 0x7fffu + ((c.u >> 16) & 1u);
  return (unsigned short)(u >> 16);
}

DEV void gload16(const void* g, void* l) {
  __builtin_amdgcn_global_load_lds((const __attribute__((address_space(1))) void*)g,
                                   (__attribute__((address_space(3))) void*)l, 16, 0, 0);
}

// ---------------- convert: fp32->bf16 (+ zero ret) ----------------
DEV void cv4(const float* __restrict__ s, unsigned short* __restrict__ d, int i) {
  const float4 a = *(const float4*)(s + i);
  ushort4 o;
  o.x = f2bf(a.x); o.y = f2bf(a.y); o.z = f2bf(a.z); o.w = f2bf(a.w);
  *(ushort4*)(d + i) = o;
}

__global__ __launch_bounds__(256) void convert_kernel(
    const float* __restrict__ q, const float* __restrict__ k, const float* __restrict__ v,
    const float* __restrict__ wq, const float* __restrict__ wk,
    const float* __restrict__ wv, const float* __restrict__ wo,
    unsigned short* __restrict__ xq, unsigned short* __restrict__ xk,
    unsigned short* __restrict__ xv, unsigned short* __restrict__ wb,
    unsigned short* __restrict__ ret)
{
  const int i = (blockIdx.x * 256 + threadIdx.x) * 4;   // grid covers 8388608 elems
  cv4(q, xq, i);
  cv4(k, xk, i);
  cv4(v, xv, i);
  ushort4 z; z.x = z.y = z.z = z.w = 0;
  *(ushort4*)(ret + i) = z;
  if (i < 4 * 1024 * 1024) {
    const int which = i >> 20, off = i & 1048575;
    const float* s = which == 0 ? wq : which == 1 ? wk : which == 2 ? wv : wo;
    cv4(s, wb + (which << 20), off);
  }
}

// ---------------- gemm_bt: C[m,n] = sum_k A[m,k]*Bt[n,k] (+bias) ----------------
// 128x128 tile, BK=64, 256 thr (4 waves 2x2), global_load_lds(16B) staging,
// mfma_f32_16x16x32_bf16. MODE 0: bf16 C row-major, bias[n].
// MODE 1: bf16 V^T output  [B,H,DK,S] (m=dk-dim 1024, n=b*1024+s), bias[m].
// MODE 2: fp32 C row-major, bias[n].
template<int MODE>
__global__ __launch_bounds__(256) void gemm_bt(
    const unsigned short* __restrict__ A, const unsigned short* __restrict__ Bt,
    const float* __restrict__ bias, void* __restrict__ Cout,
    int M, int N, int K)
{
  __shared__ __align__(16) unsigned short As[128 * 64];
  __shared__ __align__(16) unsigned short Bs[128 * 64];
  const int tid = threadIdx.x;
  const int lane = tid & 63, w = tid >> 6;
  const int wr = w >> 1, wc = w & 1;
  const int m0 = blockIdx.y * 128, n0 = blockIdx.x * 128;
  const int g = lane >> 4, ln = lane & 15;
  const f32x4 fzero = {0.f, 0.f, 0.f, 0.f};

  f32x4 acc[4][4];
#pragma unroll
  for (int i = 0; i < 4; i++)
#pragma unroll
    for (int j = 0; j < 4; j++) acc[i][j] = fzero;

  for (int k0 = 0; k0 < K; k0 += 64) {
    __syncthreads();
#pragma unroll
    for (int i = 0; i < 4; ++i) {
      const int obase = i * 4096 + w * 1024;
      const int o = obase + lane * 16;
      const int r = o >> 7, cb = o & 127;           // 128 B per tile row
      gload16(A  + (size_t)(m0 + r) * K + k0 + (cb >> 1), (char*)As + obase);
      gload16(Bt + (size_t)(n0 + r) * K + k0 + (cb >> 1), (char*)Bs + obase);
    }
    asm volatile("s_waitcnt vmcnt(0)" ::: "memory");
    __syncthreads();
#pragma unroll
    for (int kc = 0; kc < 2; ++kc) {
      const int ko = kc * 32 + g * 8;
      bf16x8 af[4], bfr[4];
#pragma unroll
      for (int mi = 0; mi < 4; ++mi)
        af[mi] = *(const bf16x8*)(As + (wr * 64 + mi * 16 + ln) * 64 + ko);
#pragma unroll
      for (int ni = 0; ni < 4; ++ni)
        bfr[ni] = *(const bf16x8*)(Bs + (wc * 64 + ni * 16 + ln) * 64 + ko);
#pragma unroll
      for (int mi = 0; mi < 4; ++mi)
#pragma unroll
        for (int ni = 0; ni < 4; ++ni)
          acc[mi][ni] = __builtin_amdgcn_mfma_f32_16x16x32_bf16(af[mi], bfr[ni], acc[mi][ni], 0, 0, 0);
    }
  }

#pragma unroll
  for (int mi = 0; mi < 4; ++mi)
#pragma unroll
    for (int ni = 0; ni < 4; ++ni) {
      const int mb = m0 + wr * 64 + mi * 16 + g * 4;
      const int n  = n0 + wc * 64 + ni * 16 + ln;
#pragma unroll
      for (int r = 0; r < 4; ++r) {
        const int m = mb + r;
        float val = acc[mi][ni][r];
        if (MODE == 0) {
          val += bias[n];
          ((unsigned short*)Cout)[(size_t)m * N + n] = f2bf(val);
        } else if (MODE == 1) {
          val += bias[m];
          const int b = n >> 10, s = n & 1023;
          const int hh = m >> 7, dk = m & 127;
          ((unsigned short*)Cout)[((size_t)((b * 8 + hh) * 128 + dk) << 10) + s] = f2bf(val);
        } else {
          val += bias[n];
          ((float*)Cout)[(size_t)m * N + n] = val;
        }
      }
    }
}

// ---------------- flash attention + fused attn_arrange ----------------
// Block = (b, h, 64 q-rows); 4 waves x 16 q-rows. KV chunks of 64.
// K LDS [64][128] and V^T LDS [128][64] XOR-swizzled (byte ^= (row&7)<<4),
// staged via global_load_lds with pre-swizzled global source.
__global__ __launch_bounds__(256) void attn_kernel(
    const unsigned short* __restrict__ Qp, const unsigned short* __restrict__ Kp,
    const unsigned short* __restrict__ VT, const int* __restrict__ cfg,
    unsigned short* __restrict__ ret)
{
  __shared__ __align__(16) unsigned short Ks[64 * 128];
  __shared__ __align__(16) unsigned short Vs[128 * 64];
  __shared__ __align__(16) unsigned short Ps[4 * 16 * 64];
  const int bx = blockIdx.x;
  const int qb = bx & 15, h = (bx >> 4) & 7, b = bx >> 7;
  const int tid = threadIdx.x, lane = tid & 63, w = tid >> 6;
  const int g = lane >> 4, ln = lane & 15;
  const int q0 = qb * 64;
  const f32x4 fzero = {0.f, 0.f, 0.f, 0.f};

  bf16x8 qf[4];
  {
    const unsigned short* qrow = Qp + ((size_t)(b * 1024 + q0 + w * 16 + ln)) * 1024 + h * 128;
#pragma unroll
    for (int kc = 0; kc < 4; kc++) qf[kc] = *(const bf16x8*)(qrow + kc * 32 + g * 8);
  }
  float m_run[4], l_run[4];
#pragma unroll
  for (int r = 0; r < 4; r++) { m_run[r] = -1e30f; l_run[r] = 0.f; }
  f32x4 o_acc[8];
#pragma unroll
  for (int i = 0; i < 8; i++) o_acc[i] = fzero;
  const float scale = 0.088388347648318447f;   // 1/sqrt(128)

  for (int kv0 = 0; kv0 < 1024; kv0 += 64) {
    __syncthreads();
#pragma unroll
    for (int i = 0; i < 4; ++i) {
      const int obase = i * 4096 + w * 1024;
      const int o = obase + lane * 16;
      {  // K chunk: rows kv, 256B/row, swizzled source
        const int r = o >> 8, cb = o & 255;
        const int csrc = cb ^ ((r & 7) << 4);
        gload16(Kp + ((size_t)(b * 1024 + kv0 + r)) * 1024 + h * 128 + (csrc >> 1), (char*)Ks + obase);
      }
      {  // V^T chunk: rows dk, 128B/row, swizzled source
        const int r = o >> 7, cb = o & 127;
        const int csrc = cb ^ ((r & 7) << 4);
        gload16(VT + ((size_t)((b * 8 + h) * 128 + r)) * 1024 + kv0 + (csrc >> 1), (char*)Vs + obase);
      }
    }
    asm volatile("s_waitcnt vmcnt(0)" ::: "memory");
    __syncthreads();

    // scores: S[q][kv] = Q . K, 16x64 tile per wave
    f32x4 sc[4];
#pragma unroll
    for (int nb = 0; nb < 4; ++nb) {
      sc[nb] = fzero;
      const int rr = nb * 16 + ln;
      const int sw = (rr & 7) << 4;
#pragma unroll
      for (int kc = 0; kc < 4; ++kc) {
        const bf16x8 kf = *(const bf16x8*)((const char*)Ks + rr * 256 + (((kc * 32 + g * 8) << 1) ^ sw));
        sc[nb] = __builtin_amdgcn_mfma_f32_16x16x32_bf16(qf[kc], kf, sc[nb], 0, 0, 0);
      }
    }

    // online softmax (rows live in 16-lane groups; r indexes 4 rows/group)
    float pvv[4][4], alpha[4];
#pragma unroll
    for (int r = 0; r < 4; r++) {
      float mx = -1e30f;
#pragma unroll
      for (int nb = 0; nb < 4; nb++) { const float s = sc[nb][r] * scale; mx = s > mx ? s : mx; }
#pragma unroll
      for (int d = 1; d < 16; d <<= 1) { const float o2 = __shfl_xor(mx, d); mx = o2 > mx ? o2 : mx; }
      const float mnew = m_run[r] > mx ? m_run[r] : mx;
      alpha[r] = __expf(m_run[r] - mnew);
      float sum = 0.f;
#pragma unroll
      for (int nb = 0; nb < 4; nb++) {
        const float p = __expf(sc[nb][r] * scale - mnew);
        pvv[nb][r] = p; sum += p;
      }
#pragma unroll
      for (int d = 1; d < 16; d <<= 1) sum += __shfl_xor(sum, d);
      l_run[r] = l_run[r] * alpha[r] + sum;
      m_run[r] = mnew;
    }
#pragma unroll
    for (int i = 0; i < 8; i++)
#pragma unroll
      for (int r = 0; r < 4; r++) o_acc[i][r] *= alpha[r];

    // P (D-layout) -> per-wave LDS (swizzled) -> A-layout frags
    {
      char* pbase = (char*)Ps + w * 2048;
#pragma unroll
      for (int nb = 0; nb < 4; nb++)
#pragma unroll
        for (int r = 0; r < 4; r++) {
          const int row = g * 4 + r;
          *(unsigned short*)(pbase + row * 128 + ((((nb * 16 + ln) << 1)) ^ ((row & 7) << 4))) = f2bf(pvv[nb][r]);
        }
    }
    bf16x8 pf[2];
#pragma unroll
    for (int kc = 0; kc < 2; kc++)
      pf[kc] = *(const bf16x8*)((const char*)Ps + w * 2048 + ln * 128 + (((kc * 32 + g * 8) << 1) ^ ((ln & 7) << 4)));

    // PV: ctx[q][dk] += P . V  (V^T rows = dk, k-contiguous)
#pragma unroll
    for (int nb2 = 0; nb2 < 8; ++nb2) {
      const int rr = nb2 * 16 + ln;
      const int sw = (rr & 7) << 4;
#pragma unroll
      for (int kc = 0; kc < 2; ++kc) {
        const bf16x8 vf = *(const bf16x8*)((const char*)Vs + rr * 128 + (((kc * 32 + g * 8) << 1) ^ sw));
        o_acc[nb2] = __builtin_amdgcn_mfma_f32_16x16x32_bf16(pf[kc], vf, o_acc[nb2], 0, 0, 0);
      }
    }
  }

  // epilogue: normalize + packed write (attn_arrange fused)
  const int d_b = 32 * (cfg[b] + 1);   // D_LIST = {32,64,96,128}
#pragma unroll
  for (int nb2 = 0; nb2 < 8; ++nb2) {
    const int dk = nb2 * 16 + ln;
    if (dk < d_b) {
#pragma unroll
      for (int r = 0; r < 4; r++) {
        const float val = o_acc[nb2][r] / l_run[r];
        ret[((size_t)(b * 1024 + q0 + w * 16 + g * 4 + r)) * 1024 + h * d_b + dk] = f2bf(val);
      }
    }
  }
}

// ---------------- launch ----------------
extern "C" void kernel_launch(void* const* d_in, const int* in_sizes, int n_in,
                              void* d_out, int out_size, void* d_ws, size_t ws_size,
                              hipStream_t stream)
{
  (void)in_sizes; (void)n_in; (void)out_size; (void)ws_size;
  const float* q   = (const float*)d_in[0];
  const float* k   = (const float*)d_in[1];
  const float* v   = (const float*)d_in[2];
  const int*   cfg = (const int*)d_in[3];
  const float* Wq  = (const float*)d_in[4];  const float* bq = (const float*)d_in[5];
  const float* Wk  = (const float*)d_in[6];  const float* bk = (const float*)d_in[7];
  const float* Wv  = (const float*)d_in[8];  const float* bv = (const float*)d_in[9];
  const float* Wo  = (const float*)d_in[10]; const float* bo = (const float*)d_in[11];

  const size_t X  = 8192ull * 1024ull;   // activation elems
  const size_t WN = 1024ull * 1024ull;   // one weight matrix elems
  char* p = (char*)d_ws;
  unsigned short* xq  = (unsigned short*)p; p += X * 2;
  unsigned short* xk  = (unsigned short*)p; p += X * 2;
  unsigned short* xv  = (unsigned short*)p; p += X * 2;
  unsigned short* wb  = (unsigned short*)p; p += 4 * WN * 2;
  unsigned short* Qp  = (unsigned short*)p; p += X * 2;
  unsigned short* Kp  = (unsigned short*)p; p += X * 2;
  unsigned short* VTp = (unsigned short*)p; p += X * 2;
  unsigned short* ret = (unsigned short*)p; p += X * 2;

  convert_kernel<<<dim3(8192), dim3(256), 0, stream>>>(q, k, v, Wq, Wk, Wv, Wo,
                                                       xq, xk, xv, wb, ret);

  gemm_bt<0><<<dim3(8, 64), dim3(256), 0, stream>>>(xq, wb + 0 * WN, bq, Qp, 8192, 1024, 1024);
  gemm_bt<0><<<dim3(8, 64), dim3(256), 0, stream>>>(xk, wb + 1 * WN, bk, Kp, 8192, 1024, 1024);
  gemm_bt<1><<<dim3(64, 8), dim3(256), 0, stream>>>(wb + 2 * WN, xv, bv, VTp, 1024, 8192, 1024);

  attn_kernel<<<dim3(1024), dim3(256), 0, stream>>>(Qp, Kp, VTp, cfg, ret);

  gemm_bt<2><<<dim3(8, 64), dim3(256), 0, stream>>>(ret, wb + 3 * WN, bo, d_out, 8192, 1024, 1024);
}

// Round 3
// 218.941 us; speedup vs baseline: 1.3421x; 1.3421x over previous
//
#include <hip/hip_runtime.h>
#include <hip/hip_bf16.h>

// Fused MHA, B=8, S=1024, H=8, DK=128, D=1024, fp32 in/out, bf16 MFMA compute.
// convert -> Qproj(pre-scaled) -> Kproj -> Vproj(transposed out) -> flash attn
// (swapped-QK in-lane softmax, dbuf prefetch, fused attn_arrange) -> out proj.

typedef __attribute__((ext_vector_type(8))) __bf16 bf16x8;
typedef __attribute__((ext_vector_type(4))) float f32x4;

#define DEV static __device__ __forceinline__

// native base-2 exp (v_exp_f32); avoids __exp2f glibc macro collision
DEV float exp2v(float x) { return __builtin_amdgcn_exp2f(x); }

DEV unsigned short f2bf(float f) {
  union { float f; unsigned int u; } c; c.f = f;
  unsigned int u = c.u + 0x7fffu + ((c.u >> 16) & 1u);
  return (unsigned short)(u >> 16);
}

DEV void gload16(const void* g, void* l) {
  __builtin_amdgcn_global_load_lds((const __attribute__((address_space(1))) void*)g,
                                   (__attribute__((address_space(3))) void*)l, 16, 0, 0);
}

// ---------------- convert: fp32->bf16 (+ zero ret) ----------------
DEV void cv4(const float* __restrict__ s, unsigned short* __restrict__ d, int i) {
  const float4 a = *(const float4*)(s + i);
  ushort4 o;
  o.x = f2bf(a.x); o.y = f2bf(a.y); o.z = f2bf(a.z); o.w = f2bf(a.w);
  *(ushort4*)(d + i) = o;
}

__global__ __launch_bounds__(256) void convert_kernel(
    const float* __restrict__ q, const float* __restrict__ k, const float* __restrict__ v,
    const float* __restrict__ wq, const float* __restrict__ wk,
    const float* __restrict__ wv, const float* __restrict__ wo,
    unsigned short* __restrict__ xq, unsigned short* __restrict__ xk,
    unsigned short* __restrict__ xv, unsigned short* __restrict__ wb,
    unsigned short* __restrict__ ret)
{
  const int i = (blockIdx.x * 256 + threadIdx.x) * 4;   // grid covers 8388608 elems
  cv4(q, xq, i);
  cv4(k, xk, i);
  cv4(v, xv, i);
  ushort4 z; z.x = z.y = z.z = z.w = 0;
  *(ushort4*)(ret + i) = z;
  if (i < 4 * 1024 * 1024) {
    const int which = i >> 20, off = i & 1048575;
    const float* s = which == 0 ? wq : which == 1 ? wk : which == 2 ? wv : wo;
    cv4(s, wb + (which << 20), off);
  }
}

// ---------------- gemm_bt: C[m,n] = (sum_k A[m,k]*Bt[n,k] + bias) * oscale ----------------
// 128x128 tile, BK=64, 256 thr (4 waves 2x2), global_load_lds(16B) staging.
// MODE 0: bf16 C row-major, bias[n]. MODE 1: bf16 V^T out [B,H,DK,S], bias[m].
// MODE 2: fp32 C row-major, bias[n].
template<int MODE>
__global__ __launch_bounds__(256) void gemm_bt(
    const unsigned short* __restrict__ A, const unsigned short* __restrict__ Bt,
    const float* __restrict__ bias, void* __restrict__ Cout,
    int M, int N, int K, float oscale)
{
  __shared__ __align__(16) unsigned short As[128 * 64];
  __shared__ __align__(16) unsigned short Bs[128 * 64];
  const int tid = threadIdx.x;
  const int lane = tid & 63, w = tid >> 6;
  const int wr = w >> 1, wc = w & 1;
  const int m0 = blockIdx.y * 128, n0 = blockIdx.x * 128;
  const int g = lane >> 4, ln = lane & 15;
  const f32x4 fzero = {0.f, 0.f, 0.f, 0.f};

  f32x4 acc[4][4];
#pragma unroll
  for (int i = 0; i < 4; i++)
#pragma unroll
    for (int j = 0; j < 4; j++) acc[i][j] = fzero;

  for (int k0 = 0; k0 < K; k0 += 64) {
    __syncthreads();
#pragma unroll
    for (int i = 0; i < 4; ++i) {
      const int obase = i * 4096 + w * 1024;
      const int o = obase + lane * 16;
      const int r = o >> 7, cb = o & 127;           // 128 B per tile row
      gload16(A  + (size_t)(m0 + r) * K + k0 + (cb >> 1), (char*)As + obase);
      gload16(Bt + (size_t)(n0 + r) * K + k0 + (cb >> 1), (char*)Bs + obase);
    }
    asm volatile("s_waitcnt vmcnt(0)" ::: "memory");
    __syncthreads();
#pragma unroll
    for (int kc = 0; kc < 2; ++kc) {
      const int ko = kc * 32 + g * 8;
      bf16x8 af[4], bfr[4];
#pragma unroll
      for (int mi = 0; mi < 4; ++mi)
        af[mi] = *(const bf16x8*)(As + (wr * 64 + mi * 16 + ln) * 64 + ko);
#pragma unroll
      for (int ni = 0; ni < 4; ++ni)
        bfr[ni] = *(const bf16x8*)(Bs + (wc * 64 + ni * 16 + ln) * 64 + ko);
#pragma unroll
      for (int mi = 0; mi < 4; ++mi)
#pragma unroll
        for (int ni = 0; ni < 4; ++ni)
          acc[mi][ni] = __builtin_amdgcn_mfma_f32_16x16x32_bf16(af[mi], bfr[ni], acc[mi][ni], 0, 0, 0);
    }
  }

#pragma unroll
  for (int mi = 0; mi < 4; ++mi)
#pragma unroll
    for (int ni = 0; ni < 4; ++ni) {
      const int mb = m0 + wr * 64 + mi * 16 + g * 4;
      const int n  = n0 + wc * 64 + ni * 16 + ln;
#pragma unroll
      for (int r = 0; r < 4; ++r) {
        const int m = mb + r;
        float val = acc[mi][ni][r];
        if (MODE == 0) {
          val = (val + bias[n]) * oscale;
          ((unsigned short*)Cout)[(size_t)m * N + n] = f2bf(val);
        } else if (MODE == 1) {
          val = (val + bias[m]) * oscale;
          const int b = n >> 10, s = n & 1023;
          const int hh = m >> 7, dk = m & 127;
          ((unsigned short*)Cout)[((size_t)((b * 8 + hh) * 128 + dk) << 10) + s] = f2bf(val);
        } else {
          val = (val + bias[n]) * oscale;
          ((float*)Cout)[(size_t)m * N + n] = val;
        }
      }
    }
}

// ---------------- flash attention + fused attn_arrange ----------------
// Block = (b, h, 64 q-rows); 4 waves x 16 q-rows. KV chunks of 64, double-buffered
// with issue-early prefetch. Swapped QK^T (mfma(K,Q) -> S^T): each lane owns one
// q-row (q = ln) -> in-lane kv-reduce + 2 shfl_xor. exp2 domain (Q pre-scaled by
// 1/sqrt(128)*log2e at the Q-proj GEMM). Defer-max rescale (THR=11.5 bits).
__global__ __launch_bounds__(256) void attn_kernel(
    const unsigned short* __restrict__ Qp, const unsigned short* __restrict__ Kp,
    const unsigned short* __restrict__ VT, const int* __restrict__ cfg,
    unsigned short* __restrict__ ret)
{
  __shared__ __align__(16) unsigned short Ks[2][64 * 128];
  __shared__ __align__(16) unsigned short Vs[2][128 * 64];
  __shared__ __align__(16) unsigned short Ps[4 * 16 * 64];
  const int bx = blockIdx.x;
  const int qb = bx & 15, h = (bx >> 4) & 7, b = bx >> 7;
  const int tid = threadIdx.x, lane = tid & 63, w = tid >> 6;
  const int g = lane >> 4, ln = lane & 15;
  const int q0 = qb * 64;
  const f32x4 fzero = {0.f, 0.f, 0.f, 0.f};

  // Q fragments: B-operand layout (col=q=ln, k-slice = kc*32+g*8). Pre-scaled.
  bf16x8 qf[4];
  {
    const unsigned short* qrow = Qp + ((size_t)(b * 1024 + q0 + w * 16 + ln)) * 1024 + h * 128;
#pragma unroll
    for (int kc = 0; kc < 4; kc++) qf[kc] = *(const bf16x8*)(qrow + kc * 32 + g * 8);
  }
  float m_run = -1e30f, l_run = 0.f;
  f32x4 o_acc[8];
#pragma unroll
  for (int i = 0; i < 8; i++) o_acc[i] = fzero;

  auto stage = [&](int buf, int kv0) {
#pragma unroll
    for (int i = 0; i < 4; ++i) {
      const int obase = i * 4096 + w * 1024;
      const int o = obase + lane * 16;
      {  // K chunk rows kv (256B/row), pre-swizzled source
        const int r = o >> 8, cb = o & 255;
        const int cs = cb ^ ((r & 7) << 4);
        gload16(Kp + ((size_t)(b * 1024 + kv0 + r)) * 1024 + h * 128 + (cs >> 1),
                (char*)Ks + buf * 16384 + obase);
      }
      {  // V^T chunk rows dk (128B/row), pre-swizzled source
        const int r = o >> 7, cb = o & 127;
        const int cs = cb ^ ((r & 7) << 4);
        gload16(VT + ((size_t)((b * 8 + h) * 128 + r)) * 1024 + kv0 + (cs >> 1),
                (char*)Vs + buf * 16384 + obase);
      }
    }
  };

  stage(0, 0);
  asm volatile("s_waitcnt vmcnt(0)" ::: "memory");
  __syncthreads();

  int cur = 0;
  for (int t = 0; t < 16; ++t) {
    if (t < 15) stage(cur ^ 1, (t + 1) * 64);   // issue-early prefetch

    // QK^T swapped: sc = S^T tile. Lane holds q=ln, kv = 16*nb + 4*g + r.
    f32x4 sc[4];
#pragma unroll
    for (int nb = 0; nb < 4; ++nb) {
      sc[nb] = fzero;
      const int rr = nb * 16 + ln;
      const int sw = (rr & 7) << 4;
#pragma unroll
      for (int kc = 0; kc < 4; ++kc) {
        const bf16x8 kf = *(const bf16x8*)((const char*)Ks + cur * 16384 + rr * 256 +
                                           (((kc * 32 + g * 8) << 1) ^ sw));
        sc[nb] = __builtin_amdgcn_mfma_f32_16x16x32_bf16(kf, qf[kc], sc[nb], 0, 0, 0);
      }
    }

    // in-lane online softmax (log2 domain) for q = q0 + w*16 + ln
    float pmax = -1e30f;
#pragma unroll
    for (int nb = 0; nb < 4; ++nb)
#pragma unroll
      for (int r = 0; r < 4; ++r) pmax = fmaxf(pmax, sc[nb][r]);
    pmax = fmaxf(pmax, __shfl_xor(pmax, 16));
    pmax = fmaxf(pmax, __shfl_xor(pmax, 32));
    if (__any(pmax > m_run + 11.5f)) {
      const float mnew = fmaxf(m_run, pmax);
      const float alpha = exp2v(m_run - mnew);
      l_run *= alpha;
      m_run = mnew;
      float ar[4];
#pragma unroll
      for (int r = 0; r < 4; ++r)
        ar[r] = __shfl(alpha, (lane & 48) | (((lane >> 4) & 3) << 2) | r);
#pragma unroll
      for (int i = 0; i < 8; i++)
#pragma unroll
        for (int r = 0; r < 4; r++) o_acc[i][r] *= ar[r];
    }
    float sum = 0.f;
    float pv[16];
#pragma unroll
    for (int nb = 0; nb < 4; ++nb)
#pragma unroll
      for (int r = 0; r < 4; ++r) {
        const float p = exp2v(sc[nb][r] - m_run);
        pv[nb * 4 + r] = p; sum += p;
      }
    sum += __shfl_xor(sum, 16);
    sum += __shfl_xor(sum, 32);
    l_run += sum;

    // P -> per-wave LDS: row q=ln (128B), byte = 2*kv ^ ((ln&7)<<4), kv = 16nb+4g+r
    {
      char* pbase = (char*)Ps + w * 2048 + ln * 128;
#pragma unroll
      for (int nb = 0; nb < 4; ++nb) {
        uint2 pk;
        pk.x = (unsigned)f2bf(pv[nb * 4 + 0]) | ((unsigned)f2bf(pv[nb * 4 + 1]) << 16);
        pk.y = (unsigned)f2bf(pv[nb * 4 + 2]) | ((unsigned)f2bf(pv[nb * 4 + 3]) << 16);
        *(uint2*)(pbase + (((16 * nb + 4 * g) << 1) ^ ((ln & 7) << 4))) = pk;
      }
    }
    // read back as PV A-operand frags: row=ln, k-slice = kc*32+g*8
    bf16x8 pf[2];
#pragma unroll
    for (int kc = 0; kc < 2; kc++)
      pf[kc] = *(const bf16x8*)((const char*)Ps + w * 2048 + ln * 128 +
                                (((kc * 32 + g * 8) << 1) ^ ((ln & 7) << 4)));

    // PV: o_acc[nb2] over dk block nb2; lane holds dk=ln+16*nb2, q rows 4g+r
#pragma unroll
    for (int nb2 = 0; nb2 < 8; ++nb2) {
      const int rr = nb2 * 16 + ln;
      const int sw = (rr & 7) << 4;
#pragma unroll
      for (int kc = 0; kc < 2; ++kc) {
        const bf16x8 vf = *(const bf16x8*)((const char*)Vs + cur * 16384 + rr * 128 +
                                           (((kc * 32 + g * 8) << 1) ^ sw));
        o_acc[nb2] = __builtin_amdgcn_mfma_f32_16x16x32_bf16(pf[kc], vf, o_acc[nb2], 0, 0, 0);
      }
    }

    asm volatile("s_waitcnt vmcnt(0)" ::: "memory");
    __syncthreads();
    cur ^= 1;
  }

  // epilogue: fetch l for q' = 4g+r, normalize, packed write (attn_arrange fused)
  float lr[4];
#pragma unroll
  for (int r = 0; r < 4; ++r)
    lr[r] = __shfl(l_run, (lane & 48) | (((lane >> 4) & 3) << 2) | r);
  const int d_b = 32 * (cfg[b] + 1);   // D_LIST = {32,64,96,128}
#pragma unroll
  for (int nb2 = 0; nb2 < 8; ++nb2) {
    const int dk = nb2 * 16 + ln;
    if (dk < d_b) {
#pragma unroll
      for (int r = 0; r < 4; r++) {
        const float val = o_acc[nb2][r] / lr[r];
        ret[((size_t)(b * 1024 + q0 + w * 16 + g * 4 + r)) * 1024 + h * d_b + dk] = f2bf(val);
      }
    }
  }
}

// ---------------- launch ----------------
extern "C" void kernel_launch(void* const* d_in, const int* in_sizes, int n_in,
                              void* d_out, int out_size, void* d_ws, size_t ws_size,
                              hipStream_t stream)
{
  (void)in_sizes; (void)n_in; (void)out_size; (void)ws_size;
  const float* q   = (const float*)d_in[0];
  const float* k   = (const float*)d_in[1];
  const float* v   = (const float*)d_in[2];
  const int*   cfg = (const int*)d_in[3];
  const float* Wq  = (const float*)d_in[4];  const float* bq = (const float*)d_in[5];
  const float* Wk  = (const float*)d_in[6];  const float* bk = (const float*)d_in[7];
  const float* Wv  = (const float*)d_in[8];  const float* bv = (const float*)d_in[9];
  const float* Wo  = (const float*)d_in[10]; const float* bo = (const float*)d_in[11];

  const size_t X  = 8192ull * 1024ull;   // activation elems
  const size_t WN = 1024ull * 1024ull;   // one weight matrix elems
  char* p = (char*)d_ws;
  unsigned short* xq  = (unsigned short*)p; p += X * 2;
  unsigned short* xk  = (unsigned short*)p; p += X * 2;
  unsigned short* xv  = (unsigned short*)p; p += X * 2;
  unsigned short* wb  = (unsigned short*)p; p += 4 * WN * 2;
  unsigned short* Qp  = (unsigned short*)p; p += X * 2;
  unsigned short* Kp  = (unsigned short*)p; p += X * 2;
  unsigned short* VTp = (unsigned short*)p; p += X * 2;
  unsigned short* ret = (unsigned short*)p; p += X * 2;

  // 1/sqrt(128) * log2(e): puts scores directly in exp2 domain
  const float QSCALE = 0.12751743f;

  convert_kernel<<<dim3(8192), dim3(256), 0, stream>>>(q, k, v, Wq, Wk, Wv, Wo,
                                                       xq, xk, xv, wb, ret);

  gemm_bt<0><<<dim3(8, 64), dim3(256), 0, stream>>>(xq, wb + 0 * WN, bq, Qp, 8192, 1024, 1024, QSCALE);
  gemm_bt<0><<<dim3(8, 64), dim3(256), 0, stream>>>(xk, wb + 1 * WN, bk, Kp, 8192, 1024, 1024, 1.0f);
  gemm_bt<1><<<dim3(64, 8), dim3(256), 0, stream>>>(wb + 2 * WN, xv, bv, VTp, 1024, 8192, 1024, 1.0f);

  attn_kernel<<<dim3(1024), dim3(256), 0, stream>>>(Qp, Kp, VTp, cfg, ret);

  gemm_bt<2><<<dim3(8, 64), dim3(256), 0, stream>>>(ret, wb + 3 * WN, bo, d_out, 8192, 1024, 1024, 1.0f);
}

// Round 4
// 204.414 us; speedup vs baseline: 1.4375x; 1.0711x over previous
//
#include <hip/hip_runtime.h>
#include <hip/hip_bf16.h>

// Fused MHA, B=8, S=1024, H=8, DK=128, D=1024, fp32 in/out, bf16 MFMA compute.
// convert -> QKV proj (one z=3 launch, V transposed epilogue) -> flash attn
// (swapped-QK in-lane softmax, cvt_pk P-pack, XCD swizzle, zero-pad fused) -> out proj.

typedef __attribute__((ext_vector_type(8))) __bf16 bf16x8;
typedef __attribute__((ext_vector_type(4))) float f32x4;

#define DEV static __device__ __forceinline__

// native base-2 exp (v_exp_f32); avoids __exp2f glibc macro collision
DEV float exp2v(float x) { return __builtin_amdgcn_exp2f(x); }

DEV unsigned short f2bf(float f) {
  union { float f; unsigned int u; } c; c.f = f;
  unsigned int u = c.u + 0x7fffu + ((c.u >> 16) & 1u);
  return (unsigned short)(u >> 16);
}

// packed f32 pair -> 2xbf16 in one u32 (lo=a, hi=b); T12 recipe (no builtin)
DEV unsigned cvtpk(float a, float b) {
  unsigned r;
  asm("v_cvt_pk_bf16_f32 %0, %1, %2" : "=v"(r) : "v"(a), "v"(b));
  return r;
}

DEV void gload16(const void* g, void* l) {
  __builtin_amdgcn_global_load_lds((const __attribute__((address_space(1))) void*)g,
                                   (__attribute__((address_space(3))) void*)l, 16, 0, 0);
}

// ---------------- convert: fp32->bf16 ----------------
DEV void cv4(const float* __restrict__ s, unsigned short* __restrict__ d, int i) {
  const float4 a = *(const float4*)(s + i);
  ushort4 o;
  o.x = f2bf(a.x); o.y = f2bf(a.y); o.z = f2bf(a.z); o.w = f2bf(a.w);
  *(ushort4*)(d + i) = o;
}

__global__ __launch_bounds__(256) void convert_kernel(
    const float* __restrict__ q, const float* __restrict__ k, const float* __restrict__ v,
    const float* __restrict__ wq, const float* __restrict__ wk,
    const float* __restrict__ wv, const float* __restrict__ wo,
    unsigned short* __restrict__ xq, unsigned short* __restrict__ xk,
    unsigned short* __restrict__ xv, unsigned short* __restrict__ wb)
{
  const int i = (blockIdx.x * 256 + threadIdx.x) * 4;   // grid covers 8388608 elems
  cv4(q, xq, i);
  cv4(k, xk, i);
  cv4(v, xv, i);
  if (i < 4 * 1024 * 1024) {
    const int which = i >> 20, off = i & 1048575;
    const float* s = which == 0 ? wq : which == 1 ? wk : which == 2 ? wv : wo;
    cv4(s, wb + (which << 20), off);
  }
}

// ---------------- QKV projection GEMM, grid (8,64,3) ----------------
// C[m,n] = sum_k X[m,k]*W[n,k] + bias[n]. M=8192 tokens, N=K=1024.
// 128x128 tile, BK=64, 256 thr (4 waves 2x2), global_load_lds(16B) staging.
// z=0: Q, bf16 row-major, pre-scaled by 1/sqrt(128)*log2e. z=1: K, bf16 row-major.
// z=2: V, transposed epilogue -> VT[b,h,dk,s] with 8B packed stores.
__global__ __launch_bounds__(256) void gemm_qkv(
    const unsigned short* __restrict__ xq, const unsigned short* __restrict__ xk,
    const unsigned short* __restrict__ xv, const unsigned short* __restrict__ wb,
    const float* __restrict__ bq, const float* __restrict__ bk, const float* __restrict__ bv,
    unsigned short* __restrict__ Qp, unsigned short* __restrict__ Kp,
    unsigned short* __restrict__ VTp)
{
  __shared__ __align__(16) unsigned short As[128 * 64];
  __shared__ __align__(16) unsigned short Bs[128 * 64];
  const int z = blockIdx.z;
  const unsigned short* A  = z == 0 ? xq : z == 1 ? xk : xv;
  const unsigned short* Bt = wb + (z << 20);
  const float* bias = z == 0 ? bq : z == 1 ? bk : bv;
  const int tid = threadIdx.x;
  const int lane = tid & 63, w = tid >> 6;
  const int wr = w >> 1, wc = w & 1;
  const int m0 = blockIdx.y * 128, n0 = blockIdx.x * 128;
  const int g = lane >> 4, ln = lane & 15;
  const f32x4 fzero = {0.f, 0.f, 0.f, 0.f};

  f32x4 acc[4][4];
#pragma unroll
  for (int i = 0; i < 4; i++)
#pragma unroll
    for (int j = 0; j < 4; j++) acc[i][j] = fzero;

  for (int k0 = 0; k0 < 1024; k0 += 64) {
    __syncthreads();
#pragma unroll
    for (int i = 0; i < 4; ++i) {
      const int obase = i * 4096 + w * 1024;
      const int o = obase + lane * 16;
      const int r = o >> 7, cb = o & 127;           // 128 B per tile row
      gload16(A  + (size_t)(m0 + r) * 1024 + k0 + (cb >> 1), (char*)As + obase);
      gload16(Bt + (size_t)(n0 + r) * 1024 + k0 + (cb >> 1), (char*)Bs + obase);
    }
    asm volatile("s_waitcnt vmcnt(0)" ::: "memory");
    __syncthreads();
#pragma unroll
    for (int kc = 0; kc < 2; ++kc) {
      const int ko = kc * 32 + g * 8;
      bf16x8 af[4], bfr[4];
#pragma unroll
      for (int mi = 0; mi < 4; ++mi)
        af[mi] = *(const bf16x8*)(As + (wr * 64 + mi * 16 + ln) * 64 + ko);
#pragma unroll
      for (int ni = 0; ni < 4; ++ni)
        bfr[ni] = *(const bf16x8*)(Bs + (wc * 64 + ni * 16 + ln) * 64 + ko);
#pragma unroll
      for (int mi = 0; mi < 4; ++mi)
#pragma unroll
        for (int ni = 0; ni < 4; ++ni)
          acc[mi][ni] = __builtin_amdgcn_mfma_f32_16x16x32_bf16(af[mi], bfr[ni], acc[mi][ni], 0, 0, 0);
    }
  }

  const float oscale = (z == 0) ? 0.12751743f : 1.0f;  // 1/sqrt(128)*log2(e) for Q
#pragma unroll
  for (int mi = 0; mi < 4; ++mi)
#pragma unroll
    for (int ni = 0; ni < 4; ++ni) {
      const int mb = m0 + wr * 64 + mi * 16 + g * 4;
      const int n  = n0 + wc * 64 + ni * 16 + ln;
      const float bn = bias[n];
      if (z < 2) {
        unsigned short* out = z == 0 ? Qp : Kp;
#pragma unroll
        for (int r = 0; r < 4; ++r)
          out[(size_t)(mb + r) * 1024 + n] = f2bf((acc[mi][ni][r] + bn) * oscale);
      } else {
        // V^T: n = h*128+dk output dim; mb..mb+3 = 4 consecutive s in one b
        const int b = mb >> 10, s0 = mb & 1023;
        uint2 pk;
        pk.x = cvtpk(acc[mi][ni][0] + bn, acc[mi][ni][1] + bn);
        pk.y = cvtpk(acc[mi][ni][2] + bn, acc[mi][ni][3] + bn);
        *(uint2*)(VTp + (((size_t)(b * 8) << 7 | n) << 10) + s0) = pk;
      }
    }
}

// ---------------- out projection GEMM: fp32 out ----------------
__global__ __launch_bounds__(256) void gemm_out(
    const unsigned short* __restrict__ A, const unsigned short* __restrict__ Bt,
    const float* __restrict__ bias, float* __restrict__ Cout)
{
  __shared__ __align__(16) unsigned short As[128 * 64];
  __shared__ __align__(16) unsigned short Bs[128 * 64];
  const int tid = threadIdx.x;
  const int lane = tid & 63, w = tid >> 6;
  const int wr = w >> 1, wc = w & 1;
  const int m0 = blockIdx.y * 128, n0 = blockIdx.x * 128;
  const int g = lane >> 4, ln = lane & 15;
  const f32x4 fzero = {0.f, 0.f, 0.f, 0.f};

  f32x4 acc[4][4];
#pragma unroll
  for (int i = 0; i < 4; i++)
#pragma unroll
    for (int j = 0; j < 4; j++) acc[i][j] = fzero;

  for (int k0 = 0; k0 < 1024; k0 += 64) {
    __syncthreads();
#pragma unroll
    for (int i = 0; i < 4; ++i) {
      const int obase = i * 4096 + w * 1024;
      const int o = obase + lane * 16;
      const int r = o >> 7, cb = o & 127;
      gload16(A  + (size_t)(m0 + r) * 1024 + k0 + (cb >> 1), (char*)As + obase);
      gload16(Bt + (size_t)(n0 + r) * 1024 + k0 + (cb >> 1), (char*)Bs + obase);
    }
    asm volatile("s_waitcnt vmcnt(0)" ::: "memory");
    __syncthreads();
#pragma unroll
    for (int kc = 0; kc < 2; ++kc) {
      const int ko = kc * 32 + g * 8;
      bf16x8 af[4], bfr[4];
#pragma unroll
      for (int mi = 0; mi < 4; ++mi)
        af[mi] = *(const bf16x8*)(As + (wr * 64 + mi * 16 + ln) * 64 + ko);
#pragma unroll
      for (int ni = 0; ni < 4; ++ni)
        bfr[ni] = *(const bf16x8*)(Bs + (wc * 64 + ni * 16 + ln) * 64 + ko);
#pragma unroll
      for (int mi = 0; mi < 4; ++mi)
#pragma unroll
        for (int ni = 0; ni < 4; ++ni)
          acc[mi][ni] = __builtin_amdgcn_mfma_f32_16x16x32_bf16(af[mi], bfr[ni], acc[mi][ni], 0, 0, 0);
    }
  }

#pragma unroll
  for (int mi = 0; mi < 4; ++mi)
#pragma unroll
    for (int ni = 0; ni < 4; ++ni) {
      const int mb = m0 + wr * 64 + mi * 16 + g * 4;
      const int n  = n0 + wc * 64 + ni * 16 + ln;
      const float bn = bias[n];
#pragma unroll
      for (int r = 0; r < 4; ++r)
        Cout[(size_t)(mb + r) * 1024 + n] = acc[mi][ni][r] + bn;
    }
}

// ---------------- flash attention + fused attn_arrange (+zero pad) ----------------
// Grid 1024, XCD-swizzled decode: bx = qb*64 + (b*8+h)  -> all 16 q-blocks of one
// (b,h) share an XCD (8 heads x 512KB KV = 4MB = one L2). 4 waves x 16 q-rows,
// KV chunks of 64 double-buffered with issue-early prefetch. Swapped QK^T:
// lane owns q=ln -> in-lane softmax (tree max + 2 shfl; l-sum deferred to epilogue).
__global__ __launch_bounds__(256) void attn_kernel(
    const unsigned short* __restrict__ Qp, const unsigned short* __restrict__ Kp,
    const unsigned short* __restrict__ VT, const int* __restrict__ cfg,
    unsigned short* __restrict__ ret)
{
  __shared__ __align__(16) unsigned short Ks[2][64 * 128];
  __shared__ __align__(16) unsigned short Vs[2][128 * 64];
  __shared__ __align__(16) unsigned short Ps[4 * 16 * 64];
  const int bx = blockIdx.x;
  const int qb = bx >> 6, bh = bx & 63, b = bh >> 3, h = bh & 7;
  const int tid = threadIdx.x, lane = tid & 63, w = tid >> 6;
  const int g = lane >> 4, ln = lane & 15;
  const int q0 = qb * 64;
  const f32x4 fzero = {0.f, 0.f, 0.f, 0.f};

  // Q fragments: B-operand layout (col=q=ln, k-slice = kc*32+g*8). Pre-scaled.
  bf16x8 qf[4];
  {
    const unsigned short* qrow = Qp + ((size_t)(b * 1024 + q0 + w * 16 + ln)) * 1024 + h * 128;
#pragma unroll
    for (int kc = 0; kc < 4; kc++) qf[kc] = *(const bf16x8*)(qrow + kc * 32 + g * 8);
  }
  float m_run = -1e30f, l_run = 0.f;   // l_run: in-lane partial (own kv quarter)
  f32x4 o_acc[8];
#pragma unroll
  for (int i = 0; i < 8; i++) o_acc[i] = fzero;

  auto stage = [&](int buf, int kv0) {
#pragma unroll
    for (int i = 0; i < 4; ++i) {
      const int obase = i * 4096 + w * 1024;
      const int o = obase + lane * 16;
      {  // K chunk rows kv (256B/row), pre-swizzled source
        const int r = o >> 8, cb = o & 255;
        const int cs = cb ^ ((r & 7) << 4);
        gload16(Kp + ((size_t)(b * 1024 + kv0 + r)) * 1024 + h * 128 + (cs >> 1),
                (char*)Ks + buf * 16384 + obase);
      }
      {  // V^T chunk rows dk (128B/row), pre-swizzled source
        const int r = o >> 7, cb = o & 127;
        const int cs = cb ^ ((r & 7) << 4);
        gload16(VT + ((size_t)((b * 8 + h) * 128 + r)) * 1024 + kv0 + (cs >> 1),
                (char*)Vs + buf * 16384 + obase);
      }
    }
  };

  stage(0, 0);
  asm volatile("s_waitcnt vmcnt(0)" ::: "memory");
  __syncthreads();

  int cur = 0;
  for (int t = 0; t < 16; ++t) {
    if (t < 15) stage(cur ^ 1, (t + 1) * 64);   // issue-early prefetch

    // QK^T swapped: sc = S^T tile. Lane holds q=ln, kv = 16*nb + 4*g + r.
    f32x4 sc[4];
    __builtin_amdgcn_s_setprio(1);
#pragma unroll
    for (int nb = 0; nb < 4; ++nb) {
      sc[nb] = fzero;
      const int rr = nb * 16 + ln;
      const int sw = (rr & 7) << 4;
#pragma unroll
      for (int kc = 0; kc < 4; ++kc) {
        const bf16x8 kf = *(const bf16x8*)((const char*)Ks + cur * 16384 + rr * 256 +
                                           (((kc * 32 + g * 8) << 1) ^ sw));
        sc[nb] = __builtin_amdgcn_mfma_f32_16x16x32_bf16(kf, qf[kc], sc[nb], 0, 0, 0);
      }
    }
    __builtin_amdgcn_s_setprio(0);

    // in-lane online softmax (log2 domain), tree max (max3-fusable)
    float mnb[4];
#pragma unroll
    for (int nb = 0; nb < 4; ++nb)
      mnb[nb] = fmaxf(fmaxf(sc[nb][0], sc[nb][1]), fmaxf(sc[nb][2], sc[nb][3]));
    float pmax = fmaxf(fmaxf(mnb[0], mnb[1]), fmaxf(mnb[2], mnb[3]));
    pmax = fmaxf(pmax, __shfl_xor(pmax, 16));
    pmax = fmaxf(pmax, __shfl_xor(pmax, 32));
    if (__any(pmax > m_run + 11.5f)) {       // defer-max: rare after chunk 0
      const float mnew = fmaxf(m_run, pmax);
      const float alpha = exp2v(m_run - mnew);
      l_run *= alpha;
      m_run = mnew;
      float ar[4];
#pragma unroll
      for (int r = 0; r < 4; ++r)
        ar[r] = __shfl(alpha, (lane & 48) | (((lane >> 4) & 3) << 2) | r);
#pragma unroll
      for (int i = 0; i < 8; i++)
#pragma unroll
        for (int r = 0; r < 4; r++) o_acc[i][r] *= ar[r];
    }
    float sum = 0.f;
    float pvv[16];
#pragma unroll
    for (int nb = 0; nb < 4; ++nb)
#pragma unroll
      for (int r = 0; r < 4; ++r) {
        const float p = exp2v(sc[nb][r] - m_run);
        pvv[nb * 4 + r] = p; sum += p;
      }
    l_run += sum;   // in-lane partial; cross-lane reduce deferred to epilogue

    // P -> per-wave LDS via cvt_pk: row q=ln (128B), byte = 2*kv ^ ((ln&7)<<4)
    {
      char* pbase = (char*)Ps + w * 2048 + ln * 128;
#pragma unroll
      for (int nb = 0; nb < 4; ++nb) {
        uint2 pk;
        pk.x = cvtpk(pvv[nb * 4 + 0], pvv[nb * 4 + 1]);
        pk.y = cvtpk(pvv[nb * 4 + 2], pvv[nb * 4 + 3]);
        *(uint2*)(pbase + (((16 * nb + 4 * g) << 1) ^ ((ln & 7) << 4))) = pk;
      }
    }
    // read back as PV A-operand frags: row=ln, k-slice = kc*32+g*8
    bf16x8 pf[2];
#pragma unroll
    for (int kc = 0; kc < 2; kc++)
      pf[kc] = *(const bf16x8*)((const char*)Ps + w * 2048 + ln * 128 +
                                (((kc * 32 + g * 8) << 1) ^ ((ln & 7) << 4)));

    // PV: o_acc[nb2] over dk block nb2; lane holds dk=ln+16*nb2, q rows 4g+r
    __builtin_amdgcn_s_setprio(1);
#pragma unroll
    for (int nb2 = 0; nb2 < 8; ++nb2) {
      const int rr = nb2 * 16 + ln;
      const int sw = (rr & 7) << 4;
#pragma unroll
      for (int kc = 0; kc < 2; ++kc) {
        const bf16x8 vf = *(const bf16x8*)((const char*)Vs + cur * 16384 + rr * 128 +
                                           (((kc * 32 + g * 8) << 1) ^ sw));
        o_acc[nb2] = __builtin_amdgcn_mfma_f32_16x16x32_bf16(pf[kc], vf, o_acc[nb2], 0, 0, 0);
      }
    }
    __builtin_amdgcn_s_setprio(0);

    asm volatile("s_waitcnt vmcnt(0)" ::: "memory");
    __syncthreads();
    cur ^= 1;
  }

  // epilogue: finish l reduce, normalize, packed write + zero pad (attn_arrange fused)
  l_run += __shfl_xor(l_run, 16);
  l_run += __shfl_xor(l_run, 32);
  float rl[4];
#pragma unroll
  for (int r = 0; r < 4; ++r)
    rl[r] = 1.0f / __shfl(l_run, (lane & 48) | (((lane >> 4) & 3) << 2) | r);
  const int d_b = 32 * (cfg[b] + 1);   // D_LIST = {32,64,96,128}
  const int zw = 128 - d_b;
  const size_t rowbase = (size_t)(b * 1024 + q0 + w * 16 + g * 4);
#pragma unroll
  for (int nb2 = 0; nb2 < 8; ++nb2) {
    const int dk = nb2 * 16 + ln;
    if (dk < d_b) {
#pragma unroll
      for (int r = 0; r < 4; r++)
        ret[(rowbase + r) * 1024 + h * d_b + dk] = f2bf(o_acc[nb2][r] * rl[r]);
    } else {
      // zero pad region: head h owns cols [8*d_b + h*zw, 8*d_b + (h+1)*zw)
#pragma unroll
      for (int r = 0; r < 4; r++)
        ret[(rowbase + r) * 1024 + 8 * d_b + h * zw + (dk - d_b)] = 0;
    }
  }
}

// ---------------- launch ----------------
extern "C" void kernel_launch(void* const* d_in, const int* in_sizes, int n_in,
                              void* d_out, int out_size, void* d_ws, size_t ws_size,
                              hipStream_t stream)
{
  (void)in_sizes; (void)n_in; (void)out_size; (void)ws_size;
  const float* q   = (const float*)d_in[0];
  const float* k   = (const float*)d_in[1];
  const float* v   = (const float*)d_in[2];
  const int*   cfg = (const int*)d_in[3];
  const float* Wq  = (const float*)d_in[4];  const float* bq = (const float*)d_in[5];
  const float* Wk  = (const float*)d_in[6];  const float* bk = (const float*)d_in[7];
  const float* Wv  = (const float*)d_in[8];  const float* bv = (const float*)d_in[9];
  const float* Wo  = (const float*)d_in[10]; const float* bo = (const float*)d_in[11];

  const size_t X  = 8192ull * 1024ull;   // activation elems
  const size_t WN = 1024ull * 1024ull;   // one weight matrix elems
  char* p = (char*)d_ws;
  unsigned short* xq  = (unsigned short*)p; p += X * 2;
  unsigned short* xk  = (unsigned short*)p; p += X * 2;
  unsigned short* xv  = (unsigned short*)p; p += X * 2;
  unsigned short* wb  = (unsigned short*)p; p += 4 * WN * 2;
  unsigned short* Qp  = (unsigned short*)p; p += X * 2;
  unsigned short* Kp  = (unsigned short*)p; p += X * 2;
  unsigned short* VTp = (unsigned short*)p; p += X * 2;
  unsigned short* ret = (unsigned short*)p; p += X * 2;

  convert_kernel<<<dim3(8192), dim3(256), 0, stream>>>(q, k, v, Wq, Wk, Wv, Wo,
                                                       xq, xk, xv, wb);

  gemm_qkv<<<dim3(8, 64, 3), dim3(256), 0, stream>>>(xq, xk, xv, wb, bq, bk, bv,
                                                     Qp, Kp, VTp);

  attn_kernel<<<dim3(1024), dim3(256), 0, stream>>>(Qp, Kp, VTp, cfg, ret);

  gemm_out<<<dim3(8, 64), dim3(256), 0, stream>>>(ret, wb + 3 * WN, bo, (float*)d_out);
}